// Round 15
// baseline (224.532 us; speedup 1.0000x reference)
//
#include <hip/hip_runtime.h>
#include <math.h>

#define S_LEN 4096
#define HID   2048
#define NH    16
#define HD    128
#define NKV   2048
#define KT    64
#define QBLK  128
#define NT    (NKV / KT)
// (1/sqrt(128)) * log2(e) -- folded into Q so QK^T lands in exp2 domain
#define QSCALE 0.12754103668587426f

typedef __attribute__((ext_vector_type(8))) _Float16 half8;
typedef __attribute__((ext_vector_type(4))) _Float16 half4;
typedef __attribute__((ext_vector_type(2))) __fp16 fp16x2;
typedef __attribute__((ext_vector_type(4))) float f32x4;
typedef __attribute__((ext_vector_type(16))) float f32x16;

#define GLB_AS __attribute__((address_space(1)))
#define LDS_AS __attribute__((address_space(3)))

#if __has_builtin(__builtin_amdgcn_exp2f)
#define EXP2(x) __builtin_amdgcn_exp2f(x)
#else
#define EXP2(x) exp2f(x)
#endif

__device__ __forceinline__ void gload16(const void* g, void* l) {
  __builtin_amdgcn_global_load_lds((GLB_AS const void*)g, (LDS_AS void*)l, 16, 0, 0);
}

__device__ __forceinline__ unsigned pkrtz(float a, float b) {
  union { fp16x2 h; unsigned u; } cv;
  cv.h = __builtin_amdgcn_cvt_pkrtz(a, b);
  return cv.u;
}

// ---------- index build ----------
__global__ void k_build_idx(const int* __restrict__ hmap, int* __restrict__ gidx) {
  int i = blockIdx.x * 256 + threadIdx.x;
  if (i < NKV) gidx[i] = hmap[2 * i];
}

// ---------- fused fp32 -> fp16 conversion for x, w_qkv, w_out ----------
#define NX8  (S_LEN * HID / 8)
#define NW8  (3 * HID * HID / 8)
#define NO8  (HID * HID / 8)
__global__ void k_cvt_all(const float* __restrict__ x, const float* __restrict__ wq,
                          const float* __restrict__ wo, _Float16* __restrict__ x16,
                          _Float16* __restrict__ wq16, _Float16* __restrict__ wo16) {
  int i = blockIdx.x * 256 + threadIdx.x;
  const float* src; _Float16* dst; int j;
  if (i < NX8)            { src = x;  dst = x16;  j = i; }
  else if (i < NX8 + NW8) { src = wq; dst = wq16; j = i - NX8; }
  else                    { src = wo; dst = wo16; j = i - NX8 - NW8; }
  float4 a = ((const float4*)src)[2 * j];
  float4 b = ((const float4*)src)[2 * j + 1];
  half8 h;
  h[0] = (_Float16)a.x; h[1] = (_Float16)a.y; h[2] = (_Float16)a.z; h[3] = (_Float16)a.w;
  h[4] = (_Float16)b.x; h[5] = (_Float16)b.y; h[6] = (_Float16)b.z; h[7] = (_Float16)b.w;
  ((half8*)dst)[j] = h;
}

// ---------- fused Q + KV GEMM: 1024 blocks, two configs co-resident ----------
// b < 512: Q part  -> q16 = x @ wq^T  (M=4096, N=2048)
// b >= 512: KV part -> swizzled K/Vt images = x[gidx] @ wkv^T (M=2048, N=4096)
__global__ __launch_bounds__(256)
void k_gemm_qkv(const _Float16* __restrict__ A, const _Float16* __restrict__ wqkv,
                _Float16* __restrict__ q16, const int* __restrict__ gidx,
                char* __restrict__ kimg, char* __restrict__ vtimg)
{
  __shared__ __align__(16) char Asl[16384];
  __shared__ __align__(16) char Bsl[16384];
  const int tid = threadIdx.x;
  const int w = tid >> 6, lane = tid & 63;
  const int l15 = lane & 15, l4 = lane >> 4;
  const int wr = w >> 1, wc = w & 1;
  const int K = HID;

  int b = blockIdx.x;
  const bool qpart = b < 512;
  int m0, n0, N;
  const _Float16* B;
  const int* arow;
  if (qpart) { m0 = (b >> 4) * 128; n0 = (b & 15) * 128; N = HID; B = wqkv; arow = nullptr; }
  else { b -= 512; m0 = (b >> 5) * 128; n0 = (b & 31) * 128; N = 2 * HID;
         B = wqkv + (size_t)HID * HID; arow = gidx; }

  const int srow  = lane >> 3;
  const int kso   = ((lane & 7) ^ srow) * 8;   // f16 elements
  const _Float16* Ap[4];
  const _Float16* Bp[4];
#pragma unroll
  for (int q = 0; q < 4; ++q) {
    int arel = m0 + 32 * w + 8 * q + srow;
    int ra = arow ? arow[arel] : arel;
    Ap[q] = A + (size_t)ra * K + kso;
    Bp[q] = B + (size_t)(n0 + 32 * w + 8 * q + srow) * K + kso;
  }

  f32x4 acc[4][4];
#pragma unroll
  for (int i = 0; i < 4; ++i)
#pragma unroll
    for (int j = 0; j < 4; ++j) acc[i][j] = (f32x4){0.f, 0.f, 0.f, 0.f};

#define STAGE_T(k0)                                                  \
  do {                                                               \
    _Pragma("unroll")                                                \
    for (int q = 0; q < 4; ++q) {                                    \
      gload16(Ap[q] + (k0), Asl + (4 * w + q) * 1024 + lane * 16);   \
      gload16(Bp[q] + (k0), Bsl + (4 * w + q) * 1024 + lane * 16);   \
    }                                                                \
  } while (0)

  STAGE_T(0);
  __syncthreads();

  const int nt = K >> 6;
  for (int t = 0; t < nt; ++t) {
    half8 af[4][2], bf[4][2];
#pragma unroll
    for (int mi = 0; mi < 4; ++mi) {
      int row = wr * 64 + mi * 16 + l15;
#pragma unroll
      for (int ks = 0; ks < 2; ++ks)
        af[mi][ks] = *(const half8*)(Asl + row * 128 + (((ks * 4 + l4) ^ (row & 7)) * 16));
    }
#pragma unroll
    for (int ni = 0; ni < 4; ++ni) {
      int row = wc * 64 + ni * 16 + l15;
#pragma unroll
      for (int ks = 0; ks < 2; ++ks)
        bf[ni][ks] = *(const half8*)(Bsl + row * 128 + (((ks * 4 + l4) ^ (row & 7)) * 16));
    }
    __syncthreads();
    if (t + 1 < nt) STAGE_T((t + 1) * 64);
    __builtin_amdgcn_s_setprio(1);
#pragma unroll
    for (int mi = 0; mi < 4; ++mi)
#pragma unroll
      for (int ni = 0; ni < 4; ++ni)
#pragma unroll
        for (int ks = 0; ks < 2; ++ks)
          acc[mi][ni] = __builtin_amdgcn_mfma_f32_16x16x32_f16(af[mi][ks], bf[ni][ks], acc[mi][ni], 0, 0, 0);
    __builtin_amdgcn_s_setprio(0);
    __syncthreads();
  }
#undef STAGE_T

  const int rbase = m0 + wr * 64 + l4 * 4;
  const int cbase = n0 + wc * 64 + l15;
#pragma unroll
  for (int mi = 0; mi < 4; ++mi)
#pragma unroll
    for (int ni = 0; ni < 4; ++ni)
#pragma unroll
      for (int e = 0; e < 4; ++e) {
        int row = rbase + mi * 16 + e;
        int col = cbase + ni * 16;
        _Float16 val = (_Float16)acc[mi][ni][e];
        if (qpart) {
          q16[(size_t)row * HID + col] = val;
        } else {
          int t = row >> 6, j = row & 63;
          if (col < HID) {
            int h = col >> 7, d = col & 127;
            int off = (h * 32 + t) * 16384 + ((j * 256 + 2 * d) ^ ((j & 7) << 4));
            *(_Float16*)(kimg + off) = val;
          } else {
            int nn = col - HID;
            int h = nn >> 7, d = nn & 127;
            int off = (h * 32 + t) * 16384 + ((d * 128 + 2 * j) ^ ((d & 7) << 4));
            *(_Float16*)(vtimg + off) = val;
          }
        }
      }
}

// ---------- out GEMM (f32 C), unchanged 128^2 structure ----------
__global__ __launch_bounds__(256)
void k_gemm_out(const _Float16* __restrict__ A, const _Float16* __restrict__ B,
                float* __restrict__ C, int M, int N, int K)
{
  __shared__ __align__(16) char Asl[16384];
  __shared__ __align__(16) char Bsl[16384];
  const int tid = threadIdx.x;
  const int w = tid >> 6, lane = tid & 63;
  const int l15 = lane & 15, l4 = lane >> 4;
  const int m0 = blockIdx.y * 128, n0 = blockIdx.x * 128;
  const int wr = w >> 1, wc = w & 1;

  const int srow  = lane >> 3;
  const int kso   = ((lane & 7) ^ srow) * 8;
  const _Float16* Ap[4];
  const _Float16* Bp[4];
#pragma unroll
  for (int q = 0; q < 4; ++q) {
    int row = m0 + 32 * w + 8 * q + srow;
    Ap[q] = A + (size_t)row * K + kso;
    Bp[q] = B + (size_t)(n0 + 32 * w + 8 * q + srow) * K + kso;
  }

  f32x4 acc[4][4];
#pragma unroll
  for (int i = 0; i < 4; ++i)
#pragma unroll
    for (int j = 0; j < 4; ++j) acc[i][j] = (f32x4){0.f, 0.f, 0.f, 0.f};

#define STAGE_T(k0)                                                  \
  do {                                                               \
    _Pragma("unroll")                                                \
    for (int q = 0; q < 4; ++q) {                                    \
      gload16(Ap[q] + (k0), Asl + (4 * w + q) * 1024 + lane * 16);   \
      gload16(Bp[q] + (k0), Bsl + (4 * w + q) * 1024 + lane * 16);   \
    }                                                                \
  } while (0)

  STAGE_T(0);
  __syncthreads();

  const int nt = K >> 6;
  for (int t = 0; t < nt; ++t) {
    half8 af[4][2], bf[4][2];
#pragma unroll
    for (int mi = 0; mi < 4; ++mi) {
      int row = wr * 64 + mi * 16 + l15;
#pragma unroll
      for (int ks = 0; ks < 2; ++ks)
        af[mi][ks] = *(const half8*)(Asl + row * 128 + (((ks * 4 + l4) ^ (row & 7)) * 16));
    }
#pragma unroll
    for (int ni = 0; ni < 4; ++ni) {
      int row = wc * 64 + ni * 16 + l15;
#pragma unroll
      for (int ks = 0; ks < 2; ++ks)
        bf[ni][ks] = *(const half8*)(Bsl + row * 128 + (((ks * 4 + l4) ^ (row & 7)) * 16));
    }
    __syncthreads();
    if (t + 1 < nt) STAGE_T((t + 1) * 64);
    __builtin_amdgcn_s_setprio(1);
#pragma unroll
    for (int mi = 0; mi < 4; ++mi)
#pragma unroll
      for (int ni = 0; ni < 4; ++ni)
#pragma unroll
        for (int ks = 0; ks < 2; ++ks)
          acc[mi][ni] = __builtin_amdgcn_mfma_f32_16x16x32_f16(af[mi][ks], bf[ni][ks], acc[mi][ni], 0, 0, 0);
    __builtin_amdgcn_s_setprio(0);
    __syncthreads();
  }
#undef STAGE_T

  const int rbase = m0 + wr * 64 + l4 * 4;
  const int cbase = n0 + wc * 64 + l15;
#pragma unroll
  for (int mi = 0; mi < 4; ++mi)
#pragma unroll
    for (int ni = 0; ni < 4; ++ni)
#pragma unroll
      for (int e = 0; e < 4; ++e)
        C[(size_t)(rbase + mi * 16 + e) * N + cbase + ni * 16] = acc[mi][ni][e];
}

// ---------- 32x32 MFMA flash attention: half-tile pipeline, 2 blocks/CU ----------
// 256 threads = 4 waves; wave owns 32 q rows (q = l&31); KV tiles of 64 split
// into two 32-j halves A/B, software-pipelined. grid = 512 (2 blocks/CU), LDS 64KB.
__global__ __launch_bounds__(256, 2)
void k_attn9(const _Float16* __restrict__ qmat, const char* __restrict__ kimg,
             const char* __restrict__ vtimg, const int* __restrict__ hmap,
             _Float16* __restrict__ att)
{
  extern __shared__ __align__(16) char lds[];
  const int tid = threadIdx.x;
  const int w = tid >> 6, lane = tid & 63;
  const int l31 = lane & 31;
  const bool hi = (lane >> 5) != 0;
  const int hib = hi ? 1 : 0;
  const int work = (blockIdx.x & 7) * 64 + (blockIdx.x >> 3);  // XCD-chunked, bijective (512)
  const int h  = work >> 5;
  const int q0 = (work & 31) * QBLK;

  half8 qf[8];
  {
    const int qrow = q0 + w * 32 + l31;
    const _Float16* qb = qmat + (size_t)qrow * HID + h * HD + hib * 8;
    const _Float16 qs = (_Float16)QSCALE;
#pragma unroll
    for (int dk = 0; dk < 8; ++dk) {
      half8 v = *(const half8*)(qb + 16 * dk);
#pragma unroll
      for (int q = 0; q < 8; ++q) v[q] *= qs;
      qf[dk] = v;
    }
  }

  const int swz = (l31 & 7) << 4;
  int koff[4], voff[4];
#pragma unroll
  for (int i = 0; i < 4; ++i) {
    koff[i] = l31 * 256 + ((i * 32 + hib * 16) ^ swz);
    voff[i] = 16384 + l31 * 128 + ((i * 32 + hib * 16) ^ swz);
  }

  const char* kbase = kimg  + (size_t)h * NT * 16384;
  const char* vbase = vtimg + (size_t)h * NT * 16384;

  f32x16 acc[4];
#pragma unroll
  for (int dt = 0; dt < 4; ++dt)
#pragma unroll
    for (int r = 0; r < 16; ++r) acc[dt][r] = 0.f;
  float lsum = 0.f;

#define STAGE(buf, t)                                                          \
  do {                                                                         \
    const char* ks_ = kbase + (size_t)(t) * 16384;                             \
    const char* vs_ = vbase + (size_t)(t) * 16384;                             \
    char* d_ = lds + (buf) * 32768;                                            \
    _Pragma("unroll")                                                          \
    for (int g = 0; g < 4; ++g) {                                              \
      gload16(ks_ + (w + 4 * g) * 1024 + lane * 16, d_ + (w + 4 * g) * 1024);  \
      gload16(vs_ + (w + 4 * g) * 1024 + lane * 16,                            \
              d_ + 16384 + (w + 4 * g) * 1024);                                \
    }                                                                          \
  } while (0)

#define SM_HALF(S, PPK)                                                        \
  do {                                                                         \
    float p_[16];                                                              \
    _Pragma("unroll")                                                          \
    for (int r = 0; r < 16; ++r) { p_[r] = EXP2((S)[r]); lsum += p_[r]; }      \
    _Pragma("unroll")                                                          \
    for (int rq = 0; rq < 4; ++rq)                                             \
      _Pragma("unroll")                                                        \
      for (int h2 = 0; h2 < 2; ++h2)                                           \
        PPK[rq][h2] = pkrtz(p_[4 * rq + 2 * h2], p_[4 * rq + 2 * h2 + 1]);     \
  } while (0)

#define PV_HALF(PPK, KSB, CUR)                                                 \
  do {                                                                         \
    _Pragma("unroll")                                                          \
    for (int k1 = 0; k1 < 2; ++k1) {                                           \
      unsigned send0 = hi ? PPK[2 * k1][0]     : PPK[2 * k1 + 1][0];           \
      unsigned send1 = hi ? PPK[2 * k1][1]     : PPK[2 * k1 + 1][1];           \
      unsigned recv0 = (unsigned)__shfl_xor((int)send0, 32);                   \
      unsigned recv1 = (unsigned)__shfl_xor((int)send1, 32);                   \
      unsigned self0 = hi ? PPK[2 * k1 + 1][0] : PPK[2 * k1][0];               \
      unsigned self1 = hi ? PPK[2 * k1 + 1][1] : PPK[2 * k1][1];               \
      union { unsigned u[4]; half8 hv; } pf;                                   \
      pf.u[0] = hi ? recv0 : self0;                                            \
      pf.u[1] = hi ? recv1 : self1;                                            \
      pf.u[2] = hi ? self0 : recv0;                                            \
      pf.u[3] = hi ? self1 : recv1;                                            \
      __builtin_amdgcn_s_setprio(1);                                           \
      _Pragma("unroll")                                                        \
      for (int dt = 0; dt < 4; ++dt) {                                         \
        half8 vf = *(const half8*)(lds + voff[(KSB) + k1] +                    \
                    ((CUR) * 32768 + dt * 4096));                              \
        acc[dt] = __builtin_amdgcn_mfma_f32_32x32x16_f16(vf, pf.hv, acc[dt], 0, 0, 0); \
      }                                                                        \
      __builtin_amdgcn_s_setprio(0);                                           \
    }                                                                          \
  } while (0)

#define QK_HALF(S, JT, CUR)                                                    \
  do {                                                                         \
    _Pragma("unroll")                                                          \
    for (int r = 0; r < 16; ++r) (S)[r] = 0.f;                                 \
    __builtin_amdgcn_s_setprio(1);                                             \
    _Pragma("unroll")                                                          \
    for (int dk = 0; dk < 8; ++dk) {                                           \
      half8 kf = *(const half8*)(lds + koff[dk & 3] +                          \
                  ((CUR) * 32768 + (JT) * 8192 + (dk >> 2) * 128));            \
      (S) = __builtin_amdgcn_mfma_f32_32x32x16_f16(kf, qf[dk], (S), 0, 0, 0);  \
    }                                                                          \
    __builtin_amdgcn_s_setprio(0);                                             \
  } while (0)

#define TILE(CUR, T)                                                           \
  do {                                                                         \
    if ((T) + 1 < NT) STAGE((CUR) ^ 1, (T) + 1);                               \
    f32x16 sA, sB;                                                             \
    QK_HALF(sA, 0, CUR);                                                       \
    QK_HALF(sB, 1, CUR);                                                       \
    unsigned PA[4][2], PB[4][2];                                               \
    SM_HALF(sA, PA);                                                           \
    PV_HALF(PA, 0, CUR);                                                       \
    SM_HALF(sB, PB);                                                           \
    PV_HALF(PB, 2, CUR);                                                       \
    asm volatile("s_waitcnt vmcnt(0)");                                        \
    __syncthreads();                                                           \
  } while (0)

  STAGE(0, 0);
  asm volatile("s_waitcnt vmcnt(0)");
  __syncthreads();

  for (int t = 0; t < NT; t += 2) {
    TILE(0, t);
    TILE(1, t + 1);
  }
#undef TILE
#undef QK_HALF
#undef PV_HALF
#undef SM_HALF
#undef STAGE

  float lt = lsum + __shfl_xor(lsum, 32);
  const float rl = 1.0f / lt;
  const int qrow = q0 + w * 32 + l31;
  const int srow = hmap[qrow];
  _Float16* ob = att + (size_t)srow * HID + h * HD;
#pragma unroll
  for (int dt = 0; dt < 4; ++dt)
#pragma unroll
    for (int rq = 0; rq < 4; ++rq) {
      const int d0 = dt * 32 + 8 * rq + 4 * hib;
      half4 o;
      o[0] = (_Float16)(acc[dt][4 * rq + 0] * rl);
      o[1] = (_Float16)(acc[dt][4 * rq + 1] * rl);
      o[2] = (_Float16)(acc[dt][4 * rq + 2] * rl);
      o[3] = (_Float16)(acc[dt][4 * rq + 3] * rl);
      *(half4*)(ob + d0) = o;
    }
}

extern "C" void kernel_launch(void* const* d_in, const int* in_sizes, int n_in,
                              void* d_out, int out_size, void* d_ws, size_t ws_size,
                              hipStream_t stream)
{
  const float* x     = (const float*)d_in[0];
  const float* w_qkv = (const float*)d_in[1];
  const float* w_out = (const float*)d_in[2];
  const int*   hmap  = (const int*)d_in[3];
  float* out = (float*)d_out;

  char* ws = (char*)d_ws;
  int* gidx = (int*)ws;                                          ws += 8192;
  _Float16* x16    = (_Float16*)ws;  // aliased with att16 (x16 dead after QKV GEMM)
  _Float16* att16  = (_Float16*)ws;                              ws += (size_t)S_LEN * HID * 2;
  _Float16* wqkv16 = (_Float16*)ws;                              ws += (size_t)3 * HID * HID * 2;
  _Float16* wout16 = (_Float16*)ws;                              ws += (size_t)HID * HID * 2;
  _Float16* q16    = (_Float16*)ws;                              ws += (size_t)S_LEN * HID * 2;
  char* kimg  = ws;                                              ws += (size_t)NH * NT * 16384;
  char* vtimg = ws;

  k_build_idx<<<8, 256, 0, stream>>>(hmap, gidx);
  k_cvt_all<<<(NX8 + NW8 + NO8 + 255) / 256, 256, 0, stream>>>(x, w_qkv, w_out,
                                                               x16, wqkv16, wout16);

  // fused: Q = x @ wq^T  AND  KV images = x[gidx] @ wkv^T (1024 blocks, 4/CU)
  k_gemm_qkv<<<1024, 256, 0, stream>>>(x16, wqkv16, q16, gidx, kimg, vtimg);

  k_attn9<<<NH * (S_LEN / QBLK), 256, 65536, stream>>>(q16, kimg, vtimg, hmap, att16);

  // out = att @ w_out^T  (4096 x 2048, fp32)
  dim3 go(HID / 128, S_LEN / 128);
  k_gemm_out<<<go, 256, 0, stream>>>(att16, wout16, out, S_LEN, HID, HID);
}

// Round 16
// 217.919 us; speedup vs baseline: 1.0303x; 1.0303x over previous
//
#include <hip/hip_runtime.h>
#include <math.h>

#define S_LEN 4096
#define HID   2048
#define NH    16
#define HD    128
#define NKV   2048
#define KT    64
#define QBLK  256
#define NT    (NKV / KT)
// (1/sqrt(128)) * log2(e) -- folded into Q so QK^T lands in exp2 domain
#define QSCALE 0.12754103668587426f

typedef __attribute__((ext_vector_type(8))) _Float16 half8;
typedef __attribute__((ext_vector_type(4))) _Float16 half4;
typedef __attribute__((ext_vector_type(2))) __fp16 fp16x2;
typedef __attribute__((ext_vector_type(4))) float f32x4;
typedef __attribute__((ext_vector_type(16))) float f32x16;

#define GLB_AS __attribute__((address_space(1)))
#define LDS_AS __attribute__((address_space(3)))

#if __has_builtin(__builtin_amdgcn_exp2f)
#define EXP2(x) __builtin_amdgcn_exp2f(x)
#else
#define EXP2(x) exp2f(x)
#endif

__device__ __forceinline__ void gload16(const void* g, void* l) {
  __builtin_amdgcn_global_load_lds((GLB_AS const void*)g, (LDS_AS void*)l, 16, 0, 0);
}

__device__ __forceinline__ unsigned pkrtz(float a, float b) {
  union { fp16x2 h; unsigned u; } cv;
  cv.h = __builtin_amdgcn_cvt_pkrtz(a, b);
  return cv.u;
}

// ---------- index build ----------
__global__ void k_build_idx(const int* __restrict__ hmap, int* __restrict__ gidx) {
  int i = blockIdx.x * 256 + threadIdx.x;
  if (i < NKV) gidx[i] = hmap[2 * i];
}

// ---------- fused fp32 -> fp16 conversion for x, w_qkv, w_out ----------
#define NX8  (S_LEN * HID / 8)
#define NW8  (3 * HID * HID / 8)
#define NO8  (HID * HID / 8)
__global__ void k_cvt_all(const float* __restrict__ x, const float* __restrict__ wq,
                          const float* __restrict__ wo, _Float16* __restrict__ x16,
                          _Float16* __restrict__ wq16, _Float16* __restrict__ wo16) {
  int i = blockIdx.x * 256 + threadIdx.x;
  const float* src; _Float16* dst; int j;
  if (i < NX8)            { src = x;  dst = x16;  j = i; }
  else if (i < NX8 + NW8) { src = wq; dst = wq16; j = i - NX8; }
  else                    { src = wo; dst = wo16; j = i - NX8 - NW8; }
  float4 a = ((const float4*)src)[2 * j];
  float4 b = ((const float4*)src)[2 * j + 1];
  half8 h;
  h[0] = (_Float16)a.x; h[1] = (_Float16)a.y; h[2] = (_Float16)a.z; h[3] = (_Float16)a.w;
  h[4] = (_Float16)b.x; h[5] = (_Float16)b.y; h[6] = (_Float16)b.z; h[7] = (_Float16)b.w;
  ((half8*)dst)[j] = h;
}

// ---------- fused Q + KV GEMM: 1024 blocks, two configs co-resident ----------
__global__ __launch_bounds__(256)
void k_gemm_qkv(const _Float16* __restrict__ A, const _Float16* __restrict__ wqkv,
                _Float16* __restrict__ q16, const int* __restrict__ gidx,
                char* __restrict__ kimg, char* __restrict__ vtimg)
{
  __shared__ __align__(16) char Asl[16384];
  __shared__ __align__(16) char Bsl[16384];
  const int tid = threadIdx.x;
  const int w = tid >> 6, lane = tid & 63;
  const int l15 = lane & 15, l4 = lane >> 4;
  const int wr = w >> 1, wc = w & 1;
  const int K = HID;

  int b = blockIdx.x;
  const bool qpart = b < 512;
  int m0, n0, N;
  const _Float16* B;
  const int* arow;
  if (qpart) { m0 = (b >> 4) * 128; n0 = (b & 15) * 128; N = HID; B = wqkv; arow = nullptr; }
  else { b -= 512; m0 = (b >> 5) * 128; n0 = (b & 31) * 128; N = 2 * HID;
         B = wqkv + (size_t)HID * HID; arow = gidx; }

  const int srow  = lane >> 3;
  const int kso   = ((lane & 7) ^ srow) * 8;   // f16 elements
  const _Float16* Ap[4];
  const _Float16* Bp[4];
#pragma unroll
  for (int q = 0; q < 4; ++q) {
    int arel = m0 + 32 * w + 8 * q + srow;
    int ra = arow ? arow[arel] : arel;
    Ap[q] = A + (size_t)ra * K + kso;
    Bp[q] = B + (size_t)(n0 + 32 * w + 8 * q + srow) * K + kso;
  }

  f32x4 acc[4][4];
#pragma unroll
  for (int i = 0; i < 4; ++i)
#pragma unroll
    for (int j = 0; j < 4; ++j) acc[i][j] = (f32x4){0.f, 0.f, 0.f, 0.f};

#define STAGE_T(k0)                                                  \
  do {                                                               \
    _Pragma("unroll")                                                \
    for (int q = 0; q < 4; ++q) {                                    \
      gload16(Ap[q] + (k0), Asl + (4 * w + q) * 1024 + lane * 16);   \
      gload16(Bp[q] + (k0), Bsl + (4 * w + q) * 1024 + lane * 16);   \
    }                                                                \
  } while (0)

  STAGE_T(0);
  __syncthreads();

  const int nt = K >> 6;
  for (int t = 0; t < nt; ++t) {
    half8 af[4][2], bf[4][2];
#pragma unroll
    for (int mi = 0; mi < 4; ++mi) {
      int row = wr * 64 + mi * 16 + l15;
#pragma unroll
      for (int ks = 0; ks < 2; ++ks)
        af[mi][ks] = *(const half8*)(Asl + row * 128 + (((ks * 4 + l4) ^ (row & 7)) * 16));
    }
#pragma unroll
    for (int ni = 0; ni < 4; ++ni) {
      int row = wc * 64 + ni * 16 + l15;
#pragma unroll
      for (int ks = 0; ks < 2; ++ks)
        bf[ni][ks] = *(const half8*)(Bsl + row * 128 + (((ks * 4 + l4) ^ (row & 7)) * 16));
    }
    __syncthreads();
    if (t + 1 < nt) STAGE_T((t + 1) * 64);
    __builtin_amdgcn_s_setprio(1);
#pragma unroll
    for (int mi = 0; mi < 4; ++mi)
#pragma unroll
      for (int ni = 0; ni < 4; ++ni)
#pragma unroll
        for (int ks = 0; ks < 2; ++ks)
          acc[mi][ni] = __builtin_amdgcn_mfma_f32_16x16x32_f16(af[mi][ks], bf[ni][ks], acc[mi][ni], 0, 0, 0);
    __builtin_amdgcn_s_setprio(0);
    __syncthreads();
  }
#undef STAGE_T

  const int rbase = m0 + wr * 64 + l4 * 4;
  const int cbase = n0 + wc * 64 + l15;
#pragma unroll
  for (int mi = 0; mi < 4; ++mi)
#pragma unroll
    for (int ni = 0; ni < 4; ++ni)
#pragma unroll
      for (int e = 0; e < 4; ++e) {
        int row = rbase + mi * 16 + e;
        int col = cbase + ni * 16;
        _Float16 val = (_Float16)acc[mi][ni][e];
        if (qpart) {
          q16[(size_t)row * HID + col] = val;
        } else {
          int t = row >> 6, j = row & 63;
          if (col < HID) {
            int h = col >> 7, d = col & 127;
            int off = (h * 32 + t) * 16384 + ((j * 256 + 2 * d) ^ ((j & 7) << 4));
            *(_Float16*)(kimg + off) = val;
          } else {
            int nn = col - HID;
            int h = nn >> 7, d = nn & 127;
            int off = (h * 32 + t) * 16384 + ((d * 128 + 2 * j) ^ ((d & 7) << 4));
            *(_Float16*)(vtimg + off) = val;
          }
        }
      }
}

// ---------- out GEMM (f32 C) ----------
__global__ __launch_bounds__(256)
void k_gemm_out(const _Float16* __restrict__ A, const _Float16* __restrict__ B,
                float* __restrict__ C, int M, int N, int K)
{
  __shared__ __align__(16) char Asl[16384];
  __shared__ __align__(16) char Bsl[16384];
  const int tid = threadIdx.x;
  const int w = tid >> 6, lane = tid & 63;
  const int l15 = lane & 15, l4 = lane >> 4;
  const int m0 = blockIdx.y * 128, n0 = blockIdx.x * 128;
  const int wr = w >> 1, wc = w & 1;

  const int srow  = lane >> 3;
  const int kso   = ((lane & 7) ^ srow) * 8;
  const _Float16* Ap[4];
  const _Float16* Bp[4];
#pragma unroll
  for (int q = 0; q < 4; ++q) {
    int row = m0 + 32 * w + 8 * q + srow;
    Ap[q] = A + (size_t)row * K + kso;
    Bp[q] = B + (size_t)(n0 + 32 * w + 8 * q + srow) * K + kso;
  }

  f32x4 acc[4][4];
#pragma unroll
  for (int i = 0; i < 4; ++i)
#pragma unroll
    for (int j = 0; j < 4; ++j) acc[i][j] = (f32x4){0.f, 0.f, 0.f, 0.f};

#define STAGE_T(k0)                                                  \
  do {                                                               \
    _Pragma("unroll")                                                \
    for (int q = 0; q < 4; ++q) {                                    \
      gload16(Ap[q] + (k0), Asl + (4 * w + q) * 1024 + lane * 16);   \
      gload16(Bp[q] + (k0), Bsl + (4 * w + q) * 1024 + lane * 16);   \
    }                                                                \
  } while (0)

  STAGE_T(0);
  __syncthreads();

  const int nt = K >> 6;
  for (int t = 0; t < nt; ++t) {
    half8 af[4][2], bf[4][2];
#pragma unroll
    for (int mi = 0; mi < 4; ++mi) {
      int row = wr * 64 + mi * 16 + l15;
#pragma unroll
      for (int ks = 0; ks < 2; ++ks)
        af[mi][ks] = *(const half8*)(Asl + row * 128 + (((ks * 4 + l4) ^ (row & 7)) * 16));
    }
#pragma unroll
    for (int ni = 0; ni < 4; ++ni) {
      int row = wc * 64 + ni * 16 + l15;
#pragma unroll
      for (int ks = 0; ks < 2; ++ks)
        bf[ni][ks] = *(const half8*)(Bsl + row * 128 + (((ks * 4 + l4) ^ (row & 7)) * 16));
    }
    __syncthreads();
    if (t + 1 < nt) STAGE_T((t + 1) * 64);
    __builtin_amdgcn_s_setprio(1);
#pragma unroll
    for (int mi = 0; mi < 4; ++mi)
#pragma unroll
      for (int ni = 0; ni < 4; ++ni)
#pragma unroll
        for (int ks = 0; ks < 2; ++ks)
          acc[mi][ni] = __builtin_amdgcn_mfma_f32_16x16x32_f16(af[mi][ks], bf[ni][ks], acc[mi][ni], 0, 0, 0);
    __builtin_amdgcn_s_setprio(0);
    __syncthreads();
  }
#undef STAGE_T

  const int rbase = m0 + wr * 64 + l4 * 4;
  const int cbase = n0 + wc * 64 + l15;
#pragma unroll
  for (int mi = 0; mi < 4; ++mi)
#pragma unroll
    for (int ni = 0; ni < 4; ++ni)
#pragma unroll
      for (int e = 0; e < 4; ++e)
        C[(size_t)(rbase + mi * 16 + e) * N + cbase + ni * 16] = acc[mi][ni][e];
}

// ---------- 32x32 MFMA flash attention: cross-tile pipeline, 4 LDS buffers ----------
// 512 threads = 8 waves; wave owns 32 q rows (q = l&31); QBLK=256, grid 256 (1/CU).
// 4 buffers x 32KB = 128KB. Stage t+3 during tile t; raw s_barrier + counted
// vmcnt(4) (never drain). Tile body interleaves SM/PV of tile t with QK of t+1.
__global__ __launch_bounds__(512, 2)
void k_attn10(const _Float16* __restrict__ qmat, const char* __restrict__ kimg,
              const char* __restrict__ vtimg, const int* __restrict__ hmap,
              _Float16* __restrict__ att)
{
  extern __shared__ __align__(16) char lds[];
  const int tid = threadIdx.x;
  const int w = tid >> 6, lane = tid & 63;
  const int l31 = lane & 31;
  const bool hi = (lane >> 5) != 0;
  const int hib = hi ? 1 : 0;
  const int work = (blockIdx.x & 7) * 32 + (blockIdx.x >> 3);  // XCD-chunked, bijective
  const int h  = work >> 4;
  const int q0 = (work & 15) * QBLK;

  half8 qf[8];
  {
    const int qrow = q0 + w * 32 + l31;
    const _Float16* qb = qmat + (size_t)qrow * HID + h * HD + hib * 8;
    const _Float16 qs = (_Float16)QSCALE;
#pragma unroll
    for (int dk = 0; dk < 8; ++dk) {
      half8 v = *(const half8*)(qb + 16 * dk);
#pragma unroll
      for (int q = 0; q < 8; ++q) v[q] *= qs;
      qf[dk] = v;
    }
  }

  const int swz = (l31 & 7) << 4;
  int koff[4], voff[4];
#pragma unroll
  for (int i = 0; i < 4; ++i) {
    koff[i] = l31 * 256 + ((i * 32 + hib * 16) ^ swz);
    voff[i] = 16384 + l31 * 128 + ((i * 32 + hib * 16) ^ swz);
  }

  const char* kbase = kimg  + (size_t)h * NT * 16384;
  const char* vbase = vtimg + (size_t)h * NT * 16384;

  f32x16 acc[4];
#pragma unroll
  for (int dt = 0; dt < 4; ++dt)
#pragma unroll
    for (int r = 0; r < 16; ++r) acc[dt][r] = 0.f;
  float lsum = 0.f;

#define STAGE(buf, t)                                                          \
  do {                                                                         \
    const char* ks_ = kbase + (size_t)(t) * 16384;                             \
    const char* vs_ = vbase + (size_t)(t) * 16384;                             \
    char* d_ = lds + (buf) * 32768;                                            \
    gload16(ks_ + w * 1024 + lane * 16,          d_ + w * 1024);               \
    gload16(ks_ + (8 + w) * 1024 + lane * 16,    d_ + (8 + w) * 1024);         \
    gload16(vs_ + w * 1024 + lane * 16,          d_ + 16384 + w * 1024);       \
    gload16(vs_ + (8 + w) * 1024 + lane * 16,    d_ + 16384 + (8 + w) * 1024); \
  } while (0)

#define SM_HALF(S, PPK)                                                        \
  do {                                                                         \
    float p_[16];                                                              \
    _Pragma("unroll")                                                          \
    for (int r = 0; r < 16; ++r) { p_[r] = EXP2((S)[r]); lsum += p_[r]; }      \
    _Pragma("unroll")                                                          \
    for (int rq = 0; rq < 4; ++rq)                                             \
      _Pragma("unroll")                                                        \
      for (int h2 = 0; h2 < 2; ++h2)                                           \
        PPK[rq][h2] = pkrtz(p_[4 * rq + 2 * h2], p_[4 * rq + 2 * h2 + 1]);     \
  } while (0)

#define PV_HALF(PPK, KSB, BUF)                                                 \
  do {                                                                         \
    _Pragma("unroll")                                                          \
    for (int k1 = 0; k1 < 2; ++k1) {                                           \
      unsigned send0 = hi ? PPK[2 * k1][0]     : PPK[2 * k1 + 1][0];           \
      unsigned send1 = hi ? PPK[2 * k1][1]     : PPK[2 * k1 + 1][1];           \
      unsigned recv0 = (unsigned)__shfl_xor((int)send0, 32);                   \
      unsigned recv1 = (unsigned)__shfl_xor((int)send1, 32);                   \
      unsigned self0 = hi ? PPK[2 * k1 + 1][0] : PPK[2 * k1][0];               \
      unsigned self1 = hi ? PPK[2 * k1 + 1][1] : PPK[2 * k1][1];               \
      union { unsigned u[4]; half8 hv; } pf;                                   \
      pf.u[0] = hi ? recv0 : self0;                                            \
      pf.u[1] = hi ? recv1 : self1;                                            \
      pf.u[2] = hi ? self0 : recv0;                                            \
      pf.u[3] = hi ? self1 : recv1;                                            \
      __builtin_amdgcn_s_setprio(1);                                           \
      _Pragma("unroll")                                                        \
      for (int dt = 0; dt < 4; ++dt) {                                         \
        half8 vf = *(const half8*)(lds + voff[(KSB) + k1] +                    \
                    ((BUF) * 32768 + dt * 4096));                              \
        acc[dt] = __builtin_amdgcn_mfma_f32_32x32x16_f16(vf, pf.hv, acc[dt], 0, 0, 0); \
      }                                                                        \
      __builtin_amdgcn_s_setprio(0);                                           \
    }                                                                          \
  } while (0)

#define QK_HALF(S, JT, BUF)                                                    \
  do {                                                                         \
    _Pragma("unroll")                                                          \
    for (int r = 0; r < 16; ++r) (S)[r] = 0.f;                                 \
    __builtin_amdgcn_s_setprio(1);                                             \
    _Pragma("unroll")                                                          \
    for (int dk = 0; dk < 8; ++dk) {                                           \
      half8 kf = *(const half8*)(lds + koff[dk & 3] +                          \
                  ((BUF) * 32768 + (JT) * 8192 + (dk >> 2) * 128));            \
      (S) = __builtin_amdgcn_mfma_f32_32x32x16_f16(kf, qf[dk], (S), 0, 0, 0);  \
    }                                                                          \
    __builtin_amdgcn_s_setprio(0);                                             \
  } while (0)

// Tile T (buffer CUR=T&3): SM/PV of T interleaved with QK of T+1 (buffer (CUR+1)&3).
#define TILE(CUR, T, DOSTAGE, DOQK, WAITASM)                                   \
  do {                                                                         \
    if (DOSTAGE) STAGE((((CUR) + 3) & 3), (T) + 3);                            \
    unsigned PA[4][2], PB[4][2];                                               \
    SM_HALF(sA, PA);                                                           \
    if (DOQK) QK_HALF(sA, 0, (((CUR) + 1) & 3));                               \
    PV_HALF(PA, 0, (CUR));                                                     \
    SM_HALF(sB, PB);                                                           \
    if (DOQK) QK_HALF(sB, 1, (((CUR) + 1) & 3));                               \
    PV_HALF(PB, 2, (CUR));                                                     \
    asm volatile(WAITASM ::: "memory");                                        \
    __builtin_amdgcn_s_barrier();                                              \
  } while (0)

  // prologue: stage tiles 0,1,2; wait for 0,1; QK(0)
  STAGE(0, 0);
  STAGE(1, 1);
  STAGE(2, 2);
  asm volatile("s_waitcnt vmcnt(4)" ::: "memory");
  __builtin_amdgcn_s_barrier();

  f32x16 sA, sB;
  QK_HALF(sA, 0, 0);
  QK_HALF(sB, 1, 0);

  for (int t = 0; t < 28; t += 4) {
    TILE(0, t + 0, true, true, "s_waitcnt vmcnt(4)");
    TILE(1, t + 1, true, true, "s_waitcnt vmcnt(4)");
    TILE(2, t + 2, true, true, "s_waitcnt vmcnt(4)");
    TILE(3, t + 3, true, true, "s_waitcnt vmcnt(4)");
  }
  TILE(0, 28, true,  true,  "s_waitcnt vmcnt(4)");   // stages tile 31
  TILE(1, 29, false, true,  "s_waitcnt vmcnt(0)");
  TILE(2, 30, false, true,  "s_waitcnt vmcnt(0)");
  TILE(3, 31, false, false, "s_waitcnt vmcnt(0)");
#undef TILE
#undef QK_HALF
#undef PV_HALF
#undef SM_HALF
#undef STAGE

  float lt = lsum + __shfl_xor(lsum, 32);
  const float rl = 1.0f / lt;
  const int qrow = q0 + w * 32 + l31;
  const int srow = hmap[qrow];
  _Float16* ob = att + (size_t)srow * HID + h * HD;
#pragma unroll
  for (int dt = 0; dt < 4; ++dt)
#pragma unroll
    for (int rq = 0; rq < 4; ++rq) {
      const int d0 = dt * 32 + 8 * rq + 4 * hib;
      half4 o;
      o[0] = (_Float16)(acc[dt][4 * rq + 0] * rl);
      o[1] = (_Float16)(acc[dt][4 * rq + 1] * rl);
      o[2] = (_Float16)(acc[dt][4 * rq + 2] * rl);
      o[3] = (_Float16)(acc[dt][4 * rq + 3] * rl);
      *(half4*)(ob + d0) = o;
    }
}

extern "C" void kernel_launch(void* const* d_in, const int* in_sizes, int n_in,
                              void* d_out, int out_size, void* d_ws, size_t ws_size,
                              hipStream_t stream)
{
  const float* x     = (const float*)d_in[0];
  const float* w_qkv = (const float*)d_in[1];
  const float* w_out = (const float*)d_in[2];
  const int*   hmap  = (const int*)d_in[3];
  float* out = (float*)d_out;

  char* ws = (char*)d_ws;
  int* gidx = (int*)ws;                                          ws += 8192;
  _Float16* x16    = (_Float16*)ws;  // aliased with att16 (x16 dead after QKV GEMM)
  _Float16* att16  = (_Float16*)ws;                              ws += (size_t)S_LEN * HID * 2;
  _Float16* wqkv16 = (_Float16*)ws;                              ws += (size_t)3 * HID * HID * 2;
  _Float16* wout16 = (_Float16*)ws;                              ws += (size_t)HID * HID * 2;
  _Float16* q16    = (_Float16*)ws;                              ws += (size_t)S_LEN * HID * 2;
  char* kimg  = ws;                                              ws += (size_t)NH * NT * 16384;
  char* vtimg = ws;

  k_build_idx<<<8, 256, 0, stream>>>(hmap, gidx);
  k_cvt_all<<<(NX8 + NW8 + NO8 + 255) / 256, 256, 0, stream>>>(x, w_qkv, w_out,
                                                               x16, wqkv16, wout16);

  // fused: Q = x @ wq^T  AND  KV images = x[gidx] @ wkv^T (1024 blocks, 4/CU)
  k_gemm_qkv<<<1024, 256, 0, stream>>>(x16, wqkv16, q16, gidx, kimg, vtimg);

  k_attn10<<<NH * (S_LEN / QBLK), 512, 131072, stream>>>(q16, kimg, vtimg, hmap, att16);

  // out = att @ w_out^T  (4096 x 2048, fp32)
  dim3 go(HID / 128, S_LEN / 128);
  k_gemm_out<<<go, 256, 0, stream>>>(att16, wout16, out, S_LEN, HID, HID);
}

// Round 17
// 213.483 us; speedup vs baseline: 1.0518x; 1.0208x over previous
//
#include <hip/hip_runtime.h>
#include <math.h>

#define S_LEN 4096
#define HID   2048
#define NH    16
#define HD    128
#define NKV   2048
#define KT    64
#define QBLK  256
#define NT    (NKV / KT)
// (1/sqrt(128)) * log2(e) -- folded into Q so QK^T lands in exp2 domain
#define QSCALE 0.12754103668587426f

typedef __attribute__((ext_vector_type(8))) _Float16 half8;
typedef __attribute__((ext_vector_type(4))) _Float16 half4;
typedef __attribute__((ext_vector_type(2))) __fp16 fp16x2;
typedef __attribute__((ext_vector_type(4))) float f32x4;
typedef __attribute__((ext_vector_type(16))) float f32x16;

#define GLB_AS __attribute__((address_space(1)))
#define LDS_AS __attribute__((address_space(3)))

#if __has_builtin(__builtin_amdgcn_exp2f)
#define EXP2(x) __builtin_amdgcn_exp2f(x)
#else
#define EXP2(x) exp2f(x)
#endif

__device__ __forceinline__ void gload16(const void* g, void* l) {
  __builtin_amdgcn_global_load_lds((GLB_AS const void*)g, (LDS_AS void*)l, 16, 0, 0);
}

__device__ __forceinline__ unsigned pkrtz(float a, float b) {
  union { fp16x2 h; unsigned u; } cv;
  cv.h = __builtin_amdgcn_cvt_pkrtz(a, b);
  return cv.u;
}

// ---------- index build ----------
__global__ void k_build_idx(const int* __restrict__ hmap, int* __restrict__ gidx) {
  int i = blockIdx.x * 256 + threadIdx.x;
  if (i < NKV) gidx[i] = hmap[2 * i];
}

// ---------- fused fp32 -> fp16 conversion for x, w_qkv, w_out ----------
#define NX8  (S_LEN * HID / 8)
#define NW8  (3 * HID * HID / 8)
#define NO8  (HID * HID / 8)
__global__ void k_cvt_all(const float* __restrict__ x, const float* __restrict__ wq,
                          const float* __restrict__ wo, _Float16* __restrict__ x16,
                          _Float16* __restrict__ wq16, _Float16* __restrict__ wo16) {
  int i = blockIdx.x * 256 + threadIdx.x;
  const float* src; _Float16* dst; int j;
  if (i < NX8)            { src = x;  dst = x16;  j = i; }
  else if (i < NX8 + NW8) { src = wq; dst = wq16; j = i - NX8; }
  else                    { src = wo; dst = wo16; j = i - NX8 - NW8; }
  float4 a = ((const float4*)src)[2 * j];
  float4 b = ((const float4*)src)[2 * j + 1];
  half8 h;
  h[0] = (_Float16)a.x; h[1] = (_Float16)a.y; h[2] = (_Float16)a.z; h[3] = (_Float16)a.w;
  h[4] = (_Float16)b.x; h[5] = (_Float16)b.y; h[6] = (_Float16)b.z; h[7] = (_Float16)b.w;
  ((half8*)dst)[j] = h;
}

// ---------- 256x256 8-phase fused Q+KV GEMM ----------
// 256 blocks = 1/CU. b<128: Q part (M=4096,N=2048); b>=128: KV part (M=2048
// gathered, N=4096 -> swizzled K/Vt images). 512 threads = 8 waves (2M x 4N).
// LDS 128KB = 2 buffers x (A 32KB + B 32KB), BK=64. Quadrants (mh,nh) in order
// (0,0),(0,1),(1,1),(1,0); per phase: ds-reads, 1 half-tile stage (2 gload16),
// barrier, 16 MFMA, [vmcnt(4) at ph4/ph8], barrier.  Race-freedom: a region is
// staged exactly 2 phases after its last read (>=1 barrier after read-drain),
// and read >=4 phases after staging, behind a vmcnt+barrier pair.
__global__ __launch_bounds__(512, 2)
void k_gemm_qkv8(const _Float16* __restrict__ A, const _Float16* __restrict__ wqkv,
                 _Float16* __restrict__ q16, const int* __restrict__ gidx,
                 char* __restrict__ kimg, char* __restrict__ vtimg)
{
  extern __shared__ __align__(16) char lds[];
  const int tid = threadIdx.x;
  const int w = tid >> 6, lane = tid & 63;
  const int l15 = lane & 15, l4 = lane >> 4;
  const int wr = w >> 2, wc = w & 3;
  const int K = HID;

  const int bid = (blockIdx.x & 7) * 32 + (blockIdx.x >> 3);  // XCD-chunked bijective
  const bool qpart = bid < 128;
  int m0, n0;
  const _Float16* B;
  if (qpart) { int b = bid;       m0 = (b >> 3) * 256; n0 = (b & 7) * 256;  B = wqkv; }
  else       { int b = bid - 128; m0 = (b >> 4) * 256; n0 = (b & 15) * 256; B = wqkv + (size_t)HID * HID; }

  // staging geometry: thread covers row r8=lane>>3 of its 8-row granule,
  // phys slot = lane&7, logical slot = (lane&7)^r8 (row-XOR swizzle)
  const int r8 = lane >> 3;
  const int sl = (lane & 7) ^ r8;
  const _Float16* ApA[2][2];
  const _Float16* BpB[2][2];
#pragma unroll
  for (int mh = 0; mh < 2; ++mh)
#pragma unroll
    for (int L = 0; L < 2; ++L) {
      int rel = L * 128 + mh * 64 + w * 8 + r8;
      int grow = qpart ? (m0 + rel) : gidx[m0 + rel];
      ApA[mh][L] = A + (size_t)grow * K + sl * 8;
    }
#pragma unroll
  for (int nh = 0; nh < 2; ++nh)
#pragma unroll
    for (int L = 0; L < 2; ++L) {
      int row = n0 + (L * 2 + (w >> 2)) * 64 + nh * 32 + (w & 3) * 8 + r8;
      BpB[nh][L] = B + (size_t)row * K + sl * 8;
    }

  // ds-read lane constants
  const int sw0 = (l4 ^ (l15 & 7)) * 16;
  const int sw1 = ((4 + l4) ^ (l15 & 7)) * 16;
  const int rofs = l15 * 128;

  f32x4 acc[8][4];
#pragma unroll
  for (int i = 0; i < 8; ++i)
#pragma unroll
    for (int j = 0; j < 4; ++j) acc[i][j] = (f32x4){0.f, 0.f, 0.f, 0.f};
  half8 af[4][2], bf[2][2];

#define STG_A(MH, BUF, T)                                                       \
  do {                                                                          \
    gload16(ApA[MH][0] + (T) * 64, lds + (BUF)*65536 + (MH)*16384 + w * 1024);  \
    gload16(ApA[MH][1] + (T) * 64, lds + (BUF)*65536 + (MH)*16384 + 8192 + w * 1024); \
  } while (0)
#define STG_B(NH, BUF, T)                                                       \
  do {                                                                          \
    gload16(BpB[NH][0] + (T) * 64, lds + (BUF)*65536 + 32768 + (NH)*16384 + w * 1024); \
    gload16(BpB[NH][1] + (T) * 64, lds + (BUF)*65536 + 32768 + (NH)*16384 + 8192 + w * 1024); \
  } while (0)

#define PH(BUF, MH, NH, LA, LB, STG, WAITS)                                     \
  do {                                                                          \
    if (LA) {                                                                   \
      _Pragma("unroll")                                                         \
      for (int j = 0; j < 4; ++j) {                                             \
        af[j][0] = *(const half8*)(lds + (BUF)*65536 + (MH)*16384 + wr * 8192 + j * 2048 + rofs + sw0); \
        af[j][1] = *(const half8*)(lds + (BUF)*65536 + (MH)*16384 + wr * 8192 + j * 2048 + rofs + sw1); \
      }                                                                         \
    }                                                                           \
    if (LB) {                                                                   \
      _Pragma("unroll")                                                         \
      for (int jn = 0; jn < 2; ++jn) {                                          \
        bf[jn][0] = *(const half8*)(lds + (BUF)*65536 + 32768 + (NH)*16384 + wc * 4096 + jn * 2048 + rofs + sw0); \
        bf[jn][1] = *(const half8*)(lds + (BUF)*65536 + 32768 + (NH)*16384 + wc * 4096 + jn * 2048 + rofs + sw1); \
      }                                                                         \
    }                                                                           \
    STG;                                                                        \
    __builtin_amdgcn_s_barrier();                                               \
    __builtin_amdgcn_s_setprio(1);                                              \
    _Pragma("unroll")                                                           \
    for (int j = 0; j < 4; ++j)                                                 \
      _Pragma("unroll")                                                         \
      for (int jn = 0; jn < 2; ++jn)                                            \
        _Pragma("unroll")                                                       \
        for (int ks = 0; ks < 2; ++ks)                                          \
          acc[(MH)*4 + j][(NH)*2 + jn] = __builtin_amdgcn_mfma_f32_16x16x32_f16( \
              af[j][ks], bf[jn][ks], acc[(MH)*4 + j][(NH)*2 + jn], 0, 0, 0);    \
    __builtin_amdgcn_s_setprio(0);                                              \
    WAITS;                                                                      \
    __builtin_amdgcn_s_barrier();                                               \
  } while (0)

  // prologue: buf0 {A0,B1,A1,B0} of K-tile 0, buf1 {A0,B1} of K-tile 1
  STG_A(0, 0, 0); STG_B(1, 0, 0); STG_A(1, 0, 0); STG_B(0, 0, 0);
  STG_A(0, 1, 1); STG_B(1, 1, 1);
  asm volatile("s_waitcnt vmcnt(4)");
  __builtin_amdgcn_s_barrier();

  for (int i = 0; i < 15; ++i) {
    const int T1 = 2 * i + 1, T2 = 2 * i + 2, T3 = 2 * i + 3;
    PH(0, 0, 0, 1, 1, STG_A(1, 1, T1), (void)0);
    PH(0, 0, 1, 0, 1, STG_B(0, 1, T1), (void)0);
    PH(0, 1, 1, 1, 0, STG_A(0, 0, T2), (void)0);
    PH(0, 1, 0, 0, 1, STG_B(1, 0, T2), asm volatile("s_waitcnt vmcnt(4)"));
    PH(1, 0, 0, 1, 1, STG_A(1, 0, T2), (void)0);
    PH(1, 0, 1, 0, 1, STG_B(0, 0, T2), (void)0);
    PH(1, 1, 1, 1, 0, STG_A(0, 1, T3), (void)0);
    PH(1, 1, 0, 0, 1, STG_B(1, 1, T3), asm volatile("s_waitcnt vmcnt(4)"));
  }
  // peeled last iteration (K-tiles 30,31): complete buf1 (tile 31), no further staging
  PH(0, 0, 0, 1, 1, STG_A(1, 1, 31), (void)0);
  PH(0, 0, 1, 0, 1, STG_B(0, 1, 31), (void)0);
  PH(0, 1, 1, 1, 0, (void)0, (void)0);
  PH(0, 1, 0, 0, 1, (void)0, asm volatile("s_waitcnt vmcnt(0)"));
  PH(1, 0, 0, 1, 1, (void)0, (void)0);
  PH(1, 0, 1, 0, 1, (void)0, (void)0);
  PH(1, 1, 1, 1, 0, (void)0, (void)0);
  PH(1, 1, 0, 0, 1, (void)0, (void)0);
#undef PH
#undef STG_A
#undef STG_B

  // epilogue: wave (wr,wc) owns rows m0+wr*128..+128, cols n0+wc*64..+64
#pragma unroll
  for (int mf = 0; mf < 8; ++mf)
#pragma unroll
    for (int nf = 0; nf < 4; ++nf)
#pragma unroll
      for (int e = 0; e < 4; ++e) {
        int row = m0 + wr * 128 + mf * 16 + l4 * 4 + e;
        int col = n0 + wc * 64 + nf * 16 + l15;
        _Float16 val = (_Float16)acc[mf][nf][e];
        if (qpart) {
          q16[(size_t)row * HID + col] = val;
        } else {
          int r = row - m0 + m0;  // gathered kv index == row (0..2047)
          int t = r >> 6, j = r & 63;
          if (col < HID) {
            int h = col >> 7, d = col & 127;
            int off = (h * 32 + t) * 16384 + ((j * 256 + 2 * d) ^ ((j & 7) << 4));
            *(_Float16*)(kimg + off) = val;
          } else {
            int nn = col - HID;
            int h = nn >> 7, d = nn & 127;
            int off = (h * 32 + t) * 16384 + ((d * 128 + 2 * j) ^ ((d & 7) << 4));
            *(_Float16*)(vtimg + off) = val;
          }
        }
      }
}

// ---------- out GEMM (f32 C), 128^2 structure ----------
__global__ __launch_bounds__(256)
void k_gemm_out(const _Float16* __restrict__ A, const _Float16* __restrict__ B,
                float* __restrict__ C, int M, int N, int K)
{
  __shared__ __align__(16) char Asl[16384];
  __shared__ __align__(16) char Bsl[16384];
  const int tid = threadIdx.x;
  const int w = tid >> 6, lane = tid & 63;
  const int l15 = lane & 15, l4 = lane >> 4;
  const int m0 = blockIdx.y * 128, n0 = blockIdx.x * 128;
  const int wr = w >> 1, wc = w & 1;

  const int srow  = lane >> 3;
  const int kso   = ((lane & 7) ^ srow) * 8;
  const _Float16* Ap[4];
  const _Float16* Bp[4];
#pragma unroll
  for (int q = 0; q < 4; ++q) {
    int row = m0 + 32 * w + 8 * q + srow;
    Ap[q] = A + (size_t)row * K + kso;
    Bp[q] = B + (size_t)(n0 + 32 * w + 8 * q + srow) * K + kso;
  }

  f32x4 acc[4][4];
#pragma unroll
  for (int i = 0; i < 4; ++i)
#pragma unroll
    for (int j = 0; j < 4; ++j) acc[i][j] = (f32x4){0.f, 0.f, 0.f, 0.f};

#define STAGE_T(k0)                                                  \
  do {                                                               \
    _Pragma("unroll")                                                \
    for (int q = 0; q < 4; ++q) {                                    \
      gload16(Ap[q] + (k0), Asl + (4 * w + q) * 1024 + lane * 16);   \
      gload16(Bp[q] + (k0), Bsl + (4 * w + q) * 1024 + lane * 16);   \
    }                                                                \
  } while (0)

  STAGE_T(0);
  __syncthreads();

  const int nt = K >> 6;
  for (int t = 0; t < nt; ++t) {
    half8 af[4][2], bf[4][2];
#pragma unroll
    for (int mi = 0; mi < 4; ++mi) {
      int row = wr * 64 + mi * 16 + l15;
#pragma unroll
      for (int ks = 0; ks < 2; ++ks)
        af[mi][ks] = *(const half8*)(Asl + row * 128 + (((ks * 4 + l4) ^ (row & 7)) * 16));
    }
#pragma unroll
    for (int ni = 0; ni < 4; ++ni) {
      int row = wc * 64 + ni * 16 + l15;
#pragma unroll
      for (int ks = 0; ks < 2; ++ks)
        bf[ni][ks] = *(const half8*)(Bsl + row * 128 + (((ks * 4 + l4) ^ (row & 7)) * 16));
    }
    __syncthreads();
    if (t + 1 < nt) STAGE_T((t + 1) * 64);
    __builtin_amdgcn_s_setprio(1);
#pragma unroll
    for (int mi = 0; mi < 4; ++mi)
#pragma unroll
      for (int ni = 0; ni < 4; ++ni)
#pragma unroll
        for (int ks = 0; ks < 2; ++ks)
          acc[mi][ni] = __builtin_amdgcn_mfma_f32_16x16x32_f16(af[mi][ks], bf[ni][ks], acc[mi][ni], 0, 0, 0);
    __builtin_amdgcn_s_setprio(0);
    __syncthreads();
  }
#undef STAGE_T

  const int rbase = m0 + wr * 64 + l4 * 4;
  const int cbase = n0 + wc * 64 + l15;
#pragma unroll
  for (int mi = 0; mi < 4; ++mi)
#pragma unroll
    for (int ni = 0; ni < 4; ++ni)
#pragma unroll
      for (int e = 0; e < 4; ++e)
        C[(size_t)(rbase + mi * 16 + e) * N + cbase + ni * 16] = acc[mi][ni][e];
}

// ---------- 32x32 MFMA flash attention: half-tile pipeline (R14 best) ----------
__global__ __launch_bounds__(512, 2)
void k_attn9(const _Float16* __restrict__ qmat, const char* __restrict__ kimg,
             const char* __restrict__ vtimg, const int* __restrict__ hmap,
             _Float16* __restrict__ att)
{
  extern __shared__ __align__(16) char lds[];
  const int tid = threadIdx.x;
  const int w = tid >> 6, lane = tid & 63;
  const int l31 = lane & 31;
  const bool hi = (lane >> 5) != 0;
  const int hib = hi ? 1 : 0;
  const int work = (blockIdx.x & 7) * 32 + (blockIdx.x >> 3);  // XCD-chunked, bijective
  const int h  = work >> 4;
  const int q0 = (work & 15) * QBLK;

  half8 qf[8];
  {
    const int qrow = q0 + w * 32 + l31;
    const _Float16* qb = qmat + (size_t)qrow * HID + h * HD + hib * 8;
    const _Float16 qs = (_Float16)QSCALE;
#pragma unroll
    for (int dk = 0; dk < 8; ++dk) {
      half8 v = *(const half8*)(qb + 16 * dk);
#pragma unroll
      for (int q = 0; q < 8; ++q) v[q] *= qs;
      qf[dk] = v;
    }
  }

  const int swz = (l31 & 7) << 4;
  int koff[4], voff[4];
#pragma unroll
  for (int i = 0; i < 4; ++i) {
    koff[i] = l31 * 256 + ((i * 32 + hib * 16) ^ swz);
    voff[i] = 16384 + l31 * 128 + ((i * 32 + hib * 16) ^ swz);
  }

  const char* kbase = kimg  + (size_t)h * NT * 16384;
  const char* vbase = vtimg + (size_t)h * NT * 16384;

  f32x16 acc[4];
#pragma unroll
  for (int dt = 0; dt < 4; ++dt)
#pragma unroll
    for (int r = 0; r < 16; ++r) acc[dt][r] = 0.f;
  float lsum = 0.f;

#define STAGE(buf, t)                                                          \
  do {                                                                         \
    const char* ks_ = kbase + (size_t)(t) * 16384;                             \
    const char* vs_ = vbase + (size_t)(t) * 16384;                             \
    char* d_ = lds + (buf) * 32768;                                            \
    gload16(ks_ + w * 1024 + lane * 16,          d_ + w * 1024);               \
    gload16(ks_ + (8 + w) * 1024 + lane * 16,    d_ + (8 + w) * 1024);         \
    gload16(vs_ + w * 1024 + lane * 16,          d_ + 16384 + w * 1024);       \
    gload16(vs_ + (8 + w) * 1024 + lane * 16,    d_ + 16384 + (8 + w) * 1024); \
  } while (0)

#define SM_HALF(S, PPK)                                                        \
  do {                                                                         \
    float p_[16];                                                              \
    _Pragma("unroll")                                                          \
    for (int r = 0; r < 16; ++r) { p_[r] = EXP2((S)[r]); lsum += p_[r]; }      \
    _Pragma("unroll")                                                          \
    for (int rq = 0; rq < 4; ++rq)                                             \
      _Pragma("unroll")                                                        \
      for (int h2 = 0; h2 < 2; ++h2)                                           \
        PPK[rq][h2] = pkrtz(p_[4 * rq + 2 * h2], p_[4 * rq + 2 * h2 + 1]);     \
  } while (0)

#define PV_HALF(PPK, KSB, CUR)                                                 \
  do {                                                                         \
    _Pragma("unroll")                                                          \
    for (int k1 = 0; k1 < 2; ++k1) {                                           \
      unsigned send0 = hi ? PPK[2 * k1][0]     : PPK[2 * k1 + 1][0];           \
      unsigned send1 = hi ? PPK[2 * k1][1]     : PPK[2 * k1 + 1][1];           \
      unsigned recv0 = (unsigned)__shfl_xor((int)send0, 32);                   \
      unsigned recv1 = (unsigned)__shfl_xor((int)send1, 32);                   \
      unsigned self0 = hi ? PPK[2 * k1 + 1][0] : PPK[2 * k1][0];               \
      unsigned self1 = hi ? PPK[2 * k1 + 1][1] : PPK[2 * k1][1];               \
      union { unsigned u[4]; half8 hv; } pf;                                   \
      pf.u[0] = hi ? recv0 : self0;                                            \
      pf.u[1] = hi ? recv1 : self1;                                            \
      pf.u[2] = hi ? self0 : recv0;                                            \
      pf.u[3] = hi ? self1 : recv1;                                            \
      __builtin_amdgcn_s_setprio(1);                                           \
      _Pragma("unroll")                                                        \
      for (int dt = 0; dt < 4; ++dt) {                                         \
        half8 vf = *(const half8*)(lds + voff[(KSB) + k1] +                    \
                    ((CUR) * 32768 + dt * 4096));                              \
        acc[dt] = __builtin_amdgcn_mfma_f32_32x32x16_f16(vf, pf.hv, acc[dt], 0, 0, 0); \
      }                                                                        \
      __builtin_amdgcn_s_setprio(0);                                           \
    }                                                                          \
  } while (0)

#define QK_HALF(S, JT, CUR)                                                    \
  do {                                                                         \
    _Pragma("unroll")                                                          \
    for (int r = 0; r < 16; ++r) (S)[r] = 0.f;                                 \
    __builtin_amdgcn_s_setprio(1);                                             \
    _Pragma("unroll")                                                          \
    for (int dk = 0; dk < 8; ++dk) {                                           \
      half8 kf = *(const half8*)(lds + koff[dk & 3] +                          \
                  ((CUR) * 32768 + (JT) * 8192 + (dk >> 2) * 128));            \
      (S) = __builtin_amdgcn_mfma_f32_32x32x16_f16(kf, qf[dk], (S), 0, 0, 0);  \
    }                                                                          \
    __builtin_amdgcn_s_setprio(0);                                             \
  } while (0)

#define TILE(CUR, T)                                                           \
  do {                                                                         \
    if ((T) + 1 < NT) STAGE((CUR) ^ 1, (T) + 1);                               \
    f32x16 sA, sB;                                                             \
    QK_HALF(sA, 0, CUR);                                                       \
    QK_HALF(sB, 1, CUR);                                                       \
    unsigned PA[4][2], PB[4][2];                                               \
    SM_HALF(sA, PA);                                                           \
    PV_HALF(PA, 0, CUR);                                                       \
    SM_HALF(sB, PB);                                                           \
    PV_HALF(PB, 2, CUR);                                                       \
    asm volatile("s_waitcnt vmcnt(0)");                                        \
    __syncthreads();                                                           \
  } while (0)

  STAGE(0, 0);
  asm volatile("s_waitcnt vmcnt(0)");
  __syncthreads();

  for (int t = 0; t < NT; t += 2) {
    TILE(0, t);
    TILE(1, t + 1);
  }
#undef TILE
#undef QK_HALF
#undef PV_HALF
#undef SM_HALF
#undef STAGE

  float lt = lsum + __shfl_xor(lsum, 32);
  const float rl = 1.0f / lt;
  const int qrow = q0 + w * 32 + l31;
  const int srow = hmap[qrow];
  _Float16* ob = att + (size_t)srow * HID + h * HD;
#pragma unroll
  for (int dt = 0; dt < 4; ++dt)
#pragma unroll
    for (int rq = 0; rq < 4; ++rq) {
      const int d0 = dt * 32 + 8 * rq + 4 * hib;
      half4 o;
      o[0] = (_Float16)(acc[dt][4 * rq + 0] * rl);
      o[1] = (_Float16)(acc[dt][4 * rq + 1] * rl);
      o[2] = (_Float16)(acc[dt][4 * rq + 2] * rl);
      o[3] = (_Float16)(acc[dt][4 * rq + 3] * rl);
      *(half4*)(ob + d0) = o;
    }
}

extern "C" void kernel_launch(void* const* d_in, const int* in_sizes, int n_in,
                              void* d_out, int out_size, void* d_ws, size_t ws_size,
                              hipStream_t stream)
{
  const float* x     = (const float*)d_in[0];
  const float* w_qkv = (const float*)d_in[1];
  const float* w_out = (const float*)d_in[2];
  const int*   hmap  = (const int*)d_in[3];
  float* out = (float*)d_out;

  char* ws = (char*)d_ws;
  int* gidx = (int*)ws;                                          ws += 8192;
  _Float16* x16    = (_Float16*)ws;  // aliased with att16 (x16 dead after QKV GEMM)
  _Float16* att16  = (_Float16*)ws;                              ws += (size_t)S_LEN * HID * 2;
  _Float16* wqkv16 = (_Float16*)ws;                              ws += (size_t)3 * HID * HID * 2;
  _Float16* wout16 = (_Float16*)ws;                              ws += (size_t)HID * HID * 2;
  _Float16* q16    = (_Float16*)ws;                              ws += (size_t)S_LEN * HID * 2;
  char* kimg  = ws;                                              ws += (size_t)NH * NT * 16384;
  char* vtimg = ws;

  k_build_idx<<<8, 256, 0, stream>>>(hmap, gidx);
  k_cvt_all<<<(NX8 + NW8 + NO8 + 255) / 256, 256, 0, stream>>>(x, w_qkv, w_out,
                                                               x16, wqkv16, wout16);

  // fused 8-phase 256^2: Q = x @ wq^T AND KV images = x[gidx] @ wkv^T
  k_gemm_qkv8<<<256, 512, 131072, stream>>>(x16, wqkv16, q16, gidx, kimg, vtimg);

  k_attn9<<<NH * (S_LEN / QBLK), 512, 65536, stream>>>(q16, kimg, vtimg, hmap, att16);

  // out = att @ w_out^T  (4096 x 2048, fp32)
  dim3 go(HID / 128, S_LEN / 128);
  k_gemm_out<<<go, 256, 0, stream>>>(att16, wout16, out, S_LEN, HID, HID);
}